// Round 6
// baseline (2245.228 us; speedup 1.0000x reference)
//
#include <hip/hip_runtime.h>
#include <hip/hip_bf16.h>

typedef float   f32x4_t  __attribute__((ext_vector_type(4)));
typedef float   f32x2_t  __attribute__((ext_vector_type(2)));
typedef __bf16  bf16x8_t __attribute__((ext_vector_type(8)));
typedef int     i32x4_t  __attribute__((ext_vector_type(4)));

#define N_ROWS   16384
#define N_COLS   1000
#define N_COLS_P 1024
#define N_DIM    512
#define N_ITER   100
#define PBLK     256
#define PTHR     512
#define NRED     64        /* reducer blocks 0..63, 16 contiguous cols each */

// ---- relaxed agent-scope (sc1) accessors: L2-bypass, coherent, no inv/wb ----
__device__ __forceinline__ float ldf_sc1(const float* p) {
    return __hip_atomic_load(p, __ATOMIC_RELAXED, __HIP_MEMORY_SCOPE_AGENT);
}
__device__ __forceinline__ void stf_sc1(float* p, float v) {
    __hip_atomic_store(p, v, __ATOMIC_RELAXED, __HIP_MEMORY_SCOPE_AGENT);
}
__device__ __forceinline__ int ldi_sc1(const int* p) {
    return __hip_atomic_load(p, __ATOMIC_RELAXED, __HIP_MEMORY_SCOPE_AGENT);
}
__device__ __forceinline__ void sti_sc1(int* p, int v) {
    __hip_atomic_store(p, v, __ATOMIC_RELAXED, __HIP_MEMORY_SCOPE_AGENT);
}
__device__ __forceinline__ void st2_sc1(float* p, float a, float b) {
    const unsigned long long u =
        ((unsigned long long)__builtin_bit_cast(unsigned, b) << 32) |
        __builtin_bit_cast(unsigned, a);
    __hip_atomic_store((unsigned long long*)p, u, __ATOMIC_RELAXED,
                       __HIP_MEMORY_SCOPE_AGENT);
}
__device__ __forceinline__ void drain_vmem() {
    asm volatile("s_waitcnt vmcnt(0)" ::: "memory");
}

__device__ __forceinline__ unsigned short f2bf(float f) {
    unsigned int u = __builtin_bit_cast(unsigned int, f);
    u += 0x7FFFu + ((u >> 16) & 1u);            // RNE round to bf16
    return (unsigned short)(u >> 16);
}

// ---------------------------------------------------------------------------
// GEMM pass: dot = F @ T^T ; K = exp(-2*s/(1-s)), s=2*dot.
// MODE 0: K as bf16 (stride 1024, zero-padded) into d_out + column partials.
// MODE 1: final plan out[i][j] = u[i]*K[i][j]*v[j] (f32, stride 1000).
// ---------------------------------------------------------------------------
template <int MODE>
__launch_bounds__(256)
__global__ void k_gemm(const float* __restrict__ F, const float* __restrict__ T,
                       void* __restrict__ Kout, float* __restrict__ cpart,
                       const float* __restrict__ v_com, const float* __restrict__ u_both,
                       const int* __restrict__ flags)
{
    __shared__ unsigned short lA[128 * 72];
    __shared__ unsigned short lB[128 * 72];
    __shared__ float cs_lds[4 * 64];

    const int bm = blockIdx.x;
    const int bn = blockIdx.y;
    const int m0 = bm << 7;
    const int n0 = bn << 7;
    const int t  = threadIdx.x;
    const int lane = t & 63;
    const int wid  = t >> 6;
    const int wr = wid >> 1;
    const int wc = wid & 1;

    f32x4_t acc[4][4];
#pragma unroll
    for (int a = 0; a < 4; ++a)
#pragma unroll
        for (int b = 0; b < 4; ++b)
            acc[a][b] = (f32x4_t){0.f, 0.f, 0.f, 0.f};

    const int srow = t >> 4;
    const int scol = (t & 15) << 2;

    for (int kt = 0; kt < N_DIM; kt += 64) {
#pragma unroll
        for (int r = 0; r < 8; ++r) {
            const int rr = srow + (r << 4);
            const float4 av = *(const float4*)(F + (size_t)(m0 + rr) * N_DIM + kt + scol);
            ushort4 a4; a4.x = f2bf(av.x); a4.y = f2bf(av.y); a4.z = f2bf(av.z); a4.w = f2bf(av.w);
            *(ushort4*)(&lA[rr * 72 + scol]) = a4;
            const int gn = n0 + rr;
            float4 bv = make_float4(0.f, 0.f, 0.f, 0.f);
            if (gn < N_COLS) bv = *(const float4*)(T + (size_t)gn * N_DIM + kt + scol);
            ushort4 b4; b4.x = f2bf(bv.x); b4.y = f2bf(bv.y); b4.z = f2bf(bv.z); b4.w = f2bf(bv.w);
            *(ushort4*)(&lB[rr * 72 + scol]) = b4;
        }
        __syncthreads();
#pragma unroll
        for (int ks = 0; ks < 2; ++ks) {
            bf16x8_t afr[4], bfr[4];
#pragma unroll
            for (int mf = 0; mf < 4; ++mf) {
                const int r = (wr << 6) + (mf << 4) + (lane & 15);
                const int off = r * 72 + (ks << 5) + ((lane >> 4) << 3);
                afr[mf] = __builtin_bit_cast(bf16x8_t, *(const i32x4_t*)(&lA[off]));
            }
#pragma unroll
            for (int nf = 0; nf < 4; ++nf) {
                const int r = (wc << 6) + (nf << 4) + (lane & 15);
                const int off = r * 72 + (ks << 5) + ((lane >> 4) << 3);
                bfr[nf] = __builtin_bit_cast(bf16x8_t, *(const i32x4_t*)(&lB[off]));
            }
#pragma unroll
            for (int mf = 0; mf < 4; ++mf)
#pragma unroll
                for (int nf = 0; nf < 4; ++nf)
                    acc[mf][nf] = __builtin_amdgcn_mfma_f32_16x16x32_bf16(
                        afr[mf], bfr[nf], acc[mf][nf], 0, 0, 0);
        }
        __syncthreads();
    }

    int usel = 2;
    if (MODE == 1) usel = flags[1];
    float csum[4] = {0.f, 0.f, 0.f, 0.f};
#pragma unroll
    for (int mf = 0; mf < 4; ++mf) {
#pragma unroll
        for (int nf = 0; nf < 4; ++nf) {
#pragma unroll
            for (int j = 0; j < 4; ++j) {
                const float d = acc[mf][nf][j];
                const float s = 2.f * d;
                const float M = s / (1.f - s);
                const float kv = __expf(-2.f * M);
                const int grow = m0 + (wr << 6) + (mf << 4) + ((lane >> 4) << 2) + j;
                const int gcol = n0 + (wc << 6) + (nf << 4) + (lane & 15);
                if (MODE == 0) {
                    ((unsigned short*)Kout)[(size_t)grow * N_COLS_P + gcol] =
                        (gcol < N_COLS) ? f2bf(kv) : (unsigned short)0;
                    csum[nf] += kv;
                } else {
                    if (gcol < N_COLS) {
                        const float u = (usel == 2) ? (1.f / 16384.f)
                                                    : u_both[(size_t)usel * N_ROWS + grow];
                        ((float*)Kout)[(size_t)grow * N_COLS + gcol] = u * kv * v_com[gcol];
                    }
                }
            }
        }
    }
    if (MODE == 0) {
#pragma unroll
        for (int nf = 0; nf < 4; ++nf) {
            csum[nf] += __shfl_xor(csum[nf], 16);
            csum[nf] += __shfl_xor(csum[nf], 32);
        }
        if (lane < 16) {
#pragma unroll
            for (int nf = 0; nf < 4; ++nf)
                cs_lds[wid * 64 + (nf << 4) + lane] = csum[nf];
        }
        __syncthreads();
        if (t < 128) {
            const int cw = t >> 6;
            const int c6 = t & 63;
            cpart[(size_t)bm * N_COLS_P + n0 + t] =
                cs_lds[cw * 64 + c6] + cs_lds[(cw + 2) * 64 + c6];
        }
    }
}

// ---------------------------------------------------------------------------
// init: ktu[0] = colsum(K)/16384 (u0=1/16384), pads=1; zero stamps/flags.
// flags: [1]=u_sel (2=uniform u0). flags2[ii] = per-iteration bad flag.
// ---------------------------------------------------------------------------
__launch_bounds__(128)
__global__ void k_init(const float* __restrict__ cpart, float* __restrict__ ktu0,
                       float* __restrict__ vcom, int* __restrict__ flags,
                       int* __restrict__ pready, int* __restrict__ rready,
                       int* __restrict__ flags2)
{
    const int j = blockIdx.x * 128 + threadIdx.x;   // 0..1023
    if (j < N_COLS) {
        float s = 0.f;
        for (int p = 0; p < 128; ++p) s += cpart[(size_t)p * N_COLS_P + j];
        ktu0[j] = s * (1.f / 16384.f);
        vcom[j] = 1.f / 1000.f;
    } else {
        ktu0[j] = 1.f;                 // pad: b=0 -> v=0 (finite)
        vcom[j] = 0.f;
    }
    if (j < PBLK) pready[j] = 0;
    if (j < NRED) rready[j] = 0;
    if (j < 128)  flags2[j] = 0;
    if (j < 4)    flags[j] = (j == 1) ? 2 : 0;
}

// ---------------------------------------------------------------------------
// Persistent Sinkhorn, 2-hop stamp protocol (no monolithic grid barrier).
// 256 blocks x 512 thr, 1 block/CU. Lane owns column pairs {128q+2*lane+e};
// 8 rows/wave; packed bf16 K in 64 VGPRs.
// Iter ii: [top: poll rready>=ii; bad(ii-1)? commit; conv(ii-1)?]
//          [A: vnew -> dots -> u -> partials; stamp pready=ii+1]
//          [B (blocks<64): poll pready>=ii+1; reduce 16 cols -> ktu[1-p];
//             stamp rready=ii+1]
// All break decisions uniform across blocks (identical local data or
// epoch-exact flags2[ii]); protocol guarantees single-buffer safety.
// ---------------------------------------------------------------------------
__launch_bounds__(PTHR, 2)
__global__ void k_persist(const unsigned short* __restrict__ Kb,
                          const float* __restrict__ ratios,
                          float* __restrict__ ktu,      // [2][1024]
                          float* __restrict__ utmp,     // [2][16384]
                          float* __restrict__ vcom,     // [1024]
                          float* __restrict__ partials, // [256][1024]
                          int* __restrict__ flags,
                          int* __restrict__ pready,     // [256]
                          int* __restrict__ rready,     // [64]
                          int* __restrict__ flags2)     // [128] per-iter bad
{
    __shared__ float vbuf[2][N_COLS_P];
    __shared__ float wp[8][N_COLS_P];
    __shared__ float redw[8][16];
    __shared__ float rbc;
    __shared__ int ibc;
    const int t = threadIdx.x, lane = t & 63, wid = t >> 6, b = blockIdx.x;
    const int row0 = (b << 6) + (wid << 3);
    const bool isred = (b < NRED);

    // K preload: packed bf16 pairs, coalesced dword loads (plain/cached).
    unsigned kp[8][8];
#pragma unroll
    for (int r = 0; r < 8; ++r) {
        const unsigned* rp = (const unsigned*)(Kb + (size_t)(row0 + r) * N_COLS_P);
#pragma unroll
        for (int q = 0; q < 8; ++q) kp[r][q] = rp[(q << 6) + lane];
    }
    const float bj0 = (t < N_COLS) ? ratios[t] * 16384.f : 0.f;
    const float bj1 = (t + PTHR < N_COLS) ? ratios[t + PTHR] * 16384.f : 0.f;

    int usel = 2;

    for (int ii = 0; ii <= N_ITER; ++ii) {
        const int p = ii & 1;
        float kc0, kc1;

        if (ii > 0) {
            // ---- top: wait for reducers of iter ii-1 ----
            if (wid == 0) {
                for (;;) {
                    const int ok = (ldi_sc1(&rready[lane]) >= ii);
                    if (__all(ok)) break;
                    __builtin_amdgcn_s_sleep(1);
                }
            }
            __syncthreads();
            // bad(ii-1)? (epoch-exact flag; settled before rready(ii-1) stamps)
            if (t == 0) ibc = ldi_sc1(&flags2[ii - 1]);
            __syncthreads();
            if (ibc) break;               // revert: usel stays at parity(ii-2)
            usel = (ii - 1) & 1;          // commit iter ii-1
            kc0 = ldf_sc1(&ktu[(p << 10) + t]);
            kc1 = ldf_sc1(&ktu[(p << 10) + t + PTHR]);
            if (((ii - 1) % 10) == 0) {   // convergence check of iter ii-1
                const float vo0 = vbuf[usel][t], vo1 = vbuf[usel][t + PTHR];
                const float d0 = (t < N_COLS) ? kc0 * vo0 - bj0 : 0.f;
                const float d1 = (t + PTHR < N_COLS) ? kc1 * vo1 - bj1 : 0.f;
                float e = d0 * d0 + d1 * d1;
#pragma unroll
                for (int sh = 1; sh <= 32; sh <<= 1) e += __shfl_xor(e, sh);
                if (lane == 0) redw[wid][0] = e;
                __syncthreads();
                if (t == 0) {
                    float s = 0.f;
#pragma unroll
                    for (int w = 0; w < 8; ++w) s += redw[w][0];
                    rbc = s;
                }
                __syncthreads();
                if (rbc < 1e-18f) break;  // converged at ii-1 (committed)
            }
            if (ii == N_ITER) break;      // epilogue-only pass
        } else {
            kc0 = ldf_sc1(&ktu[t]);
            kc1 = ldf_sc1(&ktu[t + PTHR]);
        }

        // ---- phase A: vnew (uniform badv check) ----
        const float v0 = bj0 / kc0;
        const float v1 = bj1 / kc1;
        const int badv = (kc0 == 0.f) | (kc1 == 0.f) | (!isfinite(v0)) | (!isfinite(v1));
        vbuf[p][t] = v0;
        vbuf[p][t + PTHR] = v1;
        if (__syncthreads_or(badv)) break;   // revert: usel = parity(ii-1)

        float vr[16];
#pragma unroll
        for (int q = 0; q < 8; ++q) {
            const f32x2_t vv = *(const f32x2_t*)&vbuf[p][(q << 7) + (lane << 1)];
            vr[2*q] = vv[0]; vr[2*q+1] = vv[1];
        }
        float dots[8];
#pragma unroll
        for (int r = 0; r < 8; ++r) {
            float p0 = 0.f, p1 = 0.f, p2 = 0.f, p3 = 0.f;
#pragma unroll
            for (int q = 0; q < 8; ++q) {
                const unsigned u = kp[r][q];
                const float lo = __builtin_bit_cast(float, u << 16);
                const float hi = __builtin_bit_cast(float, u & 0xFFFF0000u);
                if (q & 1) { p2 = fmaf(lo, vr[2*q], p2); p3 = fmaf(hi, vr[2*q+1], p3); }
                else       { p0 = fmaf(lo, vr[2*q], p0); p1 = fmaf(hi, vr[2*q+1], p1); }
            }
            dots[r] = (p0 + p1) + (p2 + p3);
        }
#pragma unroll
        for (int s = 1; s <= 32; s <<= 1) {
#pragma unroll
            for (int r = 0; r < 8; ++r) dots[r] += __shfl_xor(dots[r], s);
        }
        float u8[8];
        int ubad = 0;
#pragma unroll
        for (int r = 0; r < 8; ++r) { u8[r] = 1.f / dots[r]; ubad |= !isfinite(u8[r]); }
        if (lane == 0) {
            float* uo = utmp + ((size_t)p << 14) + row0;
#pragma unroll
            for (int r = 0; r < 8; ++r) uo[r] = u8[r];
        }
        if (__any(ubad) && lane == 0)
            __hip_atomic_fetch_or(&flags2[ii], 1, __ATOMIC_RELAXED,
                                  __HIP_MEMORY_SCOPE_AGENT);

        float creg[16];
#pragma unroll
        for (int e = 0; e < 16; ++e) creg[e] = 0.f;
#pragma unroll
        for (int r = 0; r < 8; ++r) {
#pragma unroll
            for (int q = 0; q < 8; ++q) {
                const unsigned u = kp[r][q];
                const float lo = __builtin_bit_cast(float, u << 16);
                const float hi = __builtin_bit_cast(float, u & 0xFFFF0000u);
                creg[2*q]   = fmaf(lo, u8[r], creg[2*q]);
                creg[2*q+1] = fmaf(hi, u8[r], creg[2*q+1]);
            }
        }
#pragma unroll
        for (int q = 0; q < 8; ++q)
            *(f32x2_t*)&wp[wid][(q << 7) + (lane << 1)] = (f32x2_t){creg[2*q], creg[2*q+1]};
        __syncthreads();
        {
            const int j2 = t << 1;
            f32x2_t s2 = *(const f32x2_t*)&wp[0][j2];
#pragma unroll
            for (int w = 1; w < 8; ++w) {
                const f32x2_t x = *(const f32x2_t*)&wp[w][j2];
                s2[0] += x[0]; s2[1] += x[1];
            }
            st2_sc1(&partials[((size_t)b << 10) + j2], s2[0], s2[1]);
        }
        drain_vmem();                     // own stores (incl. flags2 or) at L3
        __syncthreads();                  // all threads drained
        if (t == 0) sti_sc1(&pready[b], ii + 1);

        // ---- phase B: reducers (blocks 0..63) ----
        if (isred) {
            if (wid == 0) {
                for (;;) {
                    int ok = 1;
#pragma unroll
                    for (int h = 0; h < 4; ++h)
                        ok &= (ldi_sc1(&pready[(h << 6) + lane]) >= ii + 1);
                    if (__all(ok)) break;
                }
            }
            __syncthreads();
            const int col = (b << 4) + (t & 15);
            const int pr0 = t >> 4;                 // 0..31
            float s = 0.f;
#pragma unroll
            for (int k = 0; k < 8; ++k)
                s += ldf_sc1(&partials[((size_t)(pr0 + (k << 5)) << 10) + col]);
            s += __shfl_xor(s, 16);
            s += __shfl_xor(s, 32);
            if (lane < 16) redw[wid][lane] = s;
            __syncthreads();
            if (t < 16) {
                float s2 = 0.f;
#pragma unroll
                for (int w = 0; w < 8; ++w) s2 += redw[w][t];
                const int c = (b << 4) + t;
                stf_sc1(&ktu[(((ii + 1) & 1) << 10) + c], (c < N_COLS) ? s2 : 1.f);
            }
            drain_vmem();
            __syncthreads();
            if (t == 0) sti_sc1(&rready[b], ii + 1);
        }
    }

    // ---- epilogue: block 0 materializes committed v and u_sel ----
    if (b == 0) {
        float vf0, vf1;
        if (usel == 2) { vf0 = 1.f / 1000.f; vf1 = 1.f / 1000.f; }
        else           { vf0 = vbuf[usel][t]; vf1 = vbuf[usel][t + PTHR]; }
        if (t < N_COLS) vcom[t] = vf0;
        if (t + PTHR < N_COLS) vcom[t + PTHR] = vf1;
        if (t == 0) flags[1] = usel;
    }
}

extern "C" void kernel_launch(void* const* d_in, const int* in_sizes, int n_in,
                              void* d_out, int out_size, void* d_ws, size_t ws_size,
                              hipStream_t stream)
{
    const float* F      = (const float*)d_in[0];
    const float* T      = (const float*)d_in[1];
    const float* ratios = (const float*)d_in[2];
    float* out = (float*)d_out;
    unsigned short* Kb = (unsigned short*)d_out;   // bf16 K, stride 1024

    float* ws        = (float*)d_ws;
    float* partials  = ws;                                   // 256*1024
    float* ktu       = partials + (size_t)PBLK * N_COLS_P;   // 2*1024
    float* utmp      = ktu + 2 * N_COLS_P;                   // 2*16384
    float* vcom      = utmp + 2 * N_ROWS;                    // 1024
    int*   flags     = (int*)(vcom + N_COLS_P);              // 4
    int*   pready    = flags + 4;                            // 256
    int*   rready    = pready + PBLK;                        // 64
    int*   flags2    = rready + NRED;                        // 128
    const size_t need_bytes = ((size_t)PBLK * N_COLS_P + 2 * N_COLS_P + 2 * N_ROWS +
                               N_COLS_P) * sizeof(float) +
                              (4 + PBLK + NRED + 128) * sizeof(int);
    if (ws_size < need_bytes) return;

    k_gemm<0><<<dim3(128, 8), 256, 0, stream>>>(F, T, Kb, partials, nullptr, nullptr, flags);
    k_init<<<8, 128, 0, stream>>>(partials, ktu, vcom, flags, pready, rready, flags2);
    k_persist<<<PBLK, PTHR, 0, stream>>>(Kb, ratios, ktu, utmp, vcom, partials,
                                         flags, pready, rready, flags2);
    k_gemm<1><<<dim3(128, 8), 256, 0, stream>>>(F, T, out, nullptr, vcom, utmp, flags);
}

// Round 7
// 2132.690 us; speedup vs baseline: 1.0528x; 1.0528x over previous
//
#include <hip/hip_runtime.h>
#include <hip/hip_bf16.h>

typedef float   f32x4_t  __attribute__((ext_vector_type(4)));
typedef float   f32x2_t  __attribute__((ext_vector_type(2)));
typedef __bf16  bf16x8_t __attribute__((ext_vector_type(8)));
typedef int     i32x4_t  __attribute__((ext_vector_type(4)));

#define N_ROWS   16384
#define N_COLS   1000
#define N_COLS_P 1024
#define N_DIM    512
#define N_ITER   100
#define PBLK     256
#define PTHR     512
#define NRED     64        /* reducer blocks 0..63, 16 contiguous cols each */

// ---- relaxed agent-scope (sc1) accessors: coherent, no inv/wb storms ----
__device__ __forceinline__ float ldf_sc1(const float* p) {
    return __hip_atomic_load(p, __ATOMIC_RELAXED, __HIP_MEMORY_SCOPE_AGENT);
}
__device__ __forceinline__ void stf_sc1(float* p, float v) {
    __hip_atomic_store(p, v, __ATOMIC_RELAXED, __HIP_MEMORY_SCOPE_AGENT);
}
__device__ __forceinline__ int ldi_sc1(const int* p) {
    return __hip_atomic_load(p, __ATOMIC_RELAXED, __HIP_MEMORY_SCOPE_AGENT);
}
__device__ __forceinline__ void sti_sc1(int* p, int v) {
    __hip_atomic_store(p, v, __ATOMIC_RELAXED, __HIP_MEMORY_SCOPE_AGENT);
}
__device__ __forceinline__ void st2_sc1(float* p, float a, float b) {
    const unsigned long long u =
        ((unsigned long long)__builtin_bit_cast(unsigned, b) << 32) |
        __builtin_bit_cast(unsigned, a);
    __hip_atomic_store((unsigned long long*)p, u, __ATOMIC_RELAXED,
                       __HIP_MEMORY_SCOPE_AGENT);
}
__device__ __forceinline__ void drain_vmem() {
    asm volatile("s_waitcnt vmcnt(0)" ::: "memory");
}

__device__ __forceinline__ unsigned short f2bf(float f) {
    unsigned int u = __builtin_bit_cast(unsigned int, f);
    u += 0x7FFFu + ((u >> 16) & 1u);            // RNE round to bf16
    return (unsigned short)(u >> 16);
}

// ---------------------------------------------------------------------------
// GEMM pass: dot = F @ T^T ; K = exp(-2*s/(1-s)), s=2*dot.
// MODE 0: K as bf16 (stride 1024, zero-padded) into d_out + column partials.
// MODE 1: final plan out[i][j] = u[i]*K[i][j]*v[j] (f32, stride 1000).
// ---------------------------------------------------------------------------
template <int MODE>
__launch_bounds__(256)
__global__ void k_gemm(const float* __restrict__ F, const float* __restrict__ T,
                       void* __restrict__ Kout, float* __restrict__ cpart,
                       const float* __restrict__ v_com, const float* __restrict__ u_both,
                       const int* __restrict__ flags)
{
    __shared__ unsigned short lA[128 * 72];
    __shared__ unsigned short lB[128 * 72];
    __shared__ float cs_lds[4 * 64];

    const int bm = blockIdx.x;
    const int bn = blockIdx.y;
    const int m0 = bm << 7;
    const int n0 = bn << 7;
    const int t  = threadIdx.x;
    const int lane = t & 63;
    const int wid  = t >> 6;
    const int wr = wid >> 1;
    const int wc = wid & 1;

    f32x4_t acc[4][4];
#pragma unroll
    for (int a = 0; a < 4; ++a)
#pragma unroll
        for (int b = 0; b < 4; ++b)
            acc[a][b] = (f32x4_t){0.f, 0.f, 0.f, 0.f};

    const int srow = t >> 4;
    const int scol = (t & 15) << 2;

    for (int kt = 0; kt < N_DIM; kt += 64) {
#pragma unroll
        for (int r = 0; r < 8; ++r) {
            const int rr = srow + (r << 4);
            const float4 av = *(const float4*)(F + (size_t)(m0 + rr) * N_DIM + kt + scol);
            ushort4 a4; a4.x = f2bf(av.x); a4.y = f2bf(av.y); a4.z = f2bf(av.z); a4.w = f2bf(av.w);
            *(ushort4*)(&lA[rr * 72 + scol]) = a4;
            const int gn = n0 + rr;
            float4 bv = make_float4(0.f, 0.f, 0.f, 0.f);
            if (gn < N_COLS) bv = *(const float4*)(T + (size_t)gn * N_DIM + kt + scol);
            ushort4 b4; b4.x = f2bf(bv.x); b4.y = f2bf(bv.y); b4.z = f2bf(bv.z); b4.w = f2bf(bv.w);
            *(ushort4*)(&lB[rr * 72 + scol]) = b4;
        }
        __syncthreads();
#pragma unroll
        for (int ks = 0; ks < 2; ++ks) {
            bf16x8_t afr[4], bfr[4];
#pragma unroll
            for (int mf = 0; mf < 4; ++mf) {
                const int r = (wr << 6) + (mf << 4) + (lane & 15);
                const int off = r * 72 + (ks << 5) + ((lane >> 4) << 3);
                afr[mf] = __builtin_bit_cast(bf16x8_t, *(const i32x4_t*)(&lA[off]));
            }
#pragma unroll
            for (int nf = 0; nf < 4; ++nf) {
                const int r = (wc << 6) + (nf << 4) + (lane & 15);
                const int off = r * 72 + (ks << 5) + ((lane >> 4) << 3);
                bfr[nf] = __builtin_bit_cast(bf16x8_t, *(const i32x4_t*)(&lB[off]));
            }
#pragma unroll
            for (int mf = 0; mf < 4; ++mf)
#pragma unroll
                for (int nf = 0; nf < 4; ++nf)
                    acc[mf][nf] = __builtin_amdgcn_mfma_f32_16x16x32_bf16(
                        afr[mf], bfr[nf], acc[mf][nf], 0, 0, 0);
        }
        __syncthreads();
    }

    int usel = 2;
    if (MODE == 1) usel = flags[1];
    float csum[4] = {0.f, 0.f, 0.f, 0.f};
#pragma unroll
    for (int mf = 0; mf < 4; ++mf) {
#pragma unroll
        for (int nf = 0; nf < 4; ++nf) {
#pragma unroll
            for (int j = 0; j < 4; ++j) {
                const float d = acc[mf][nf][j];
                const float s = 2.f * d;
                const float M = s / (1.f - s);
                const float kv = __expf(-2.f * M);
                const int grow = m0 + (wr << 6) + (mf << 4) + ((lane >> 4) << 2) + j;
                const int gcol = n0 + (wc << 6) + (nf << 4) + (lane & 15);
                if (MODE == 0) {
                    ((unsigned short*)Kout)[(size_t)grow * N_COLS_P + gcol] =
                        (gcol < N_COLS) ? f2bf(kv) : (unsigned short)0;
                    csum[nf] += kv;
                } else {
                    if (gcol < N_COLS) {
                        const float u = (usel == 2) ? (1.f / 16384.f)
                                                    : u_both[(size_t)usel * N_ROWS + grow];
                        ((float*)Kout)[(size_t)grow * N_COLS + gcol] = u * kv * v_com[gcol];
                    }
                }
            }
        }
    }
    if (MODE == 0) {
#pragma unroll
        for (int nf = 0; nf < 4; ++nf) {
            csum[nf] += __shfl_xor(csum[nf], 16);
            csum[nf] += __shfl_xor(csum[nf], 32);
        }
        if (lane < 16) {
#pragma unroll
            for (int nf = 0; nf < 4; ++nf)
                cs_lds[wid * 64 + (nf << 4) + lane] = csum[nf];
        }
        __syncthreads();
        if (t < 128) {
            const int cw = t >> 6;
            const int c6 = t & 63;
            cpart[(size_t)bm * N_COLS_P + n0 + t] =
                cs_lds[cw * 64 + c6] + cs_lds[(cw + 2) * 64 + c6];
        }
    }
}

// ---------------------------------------------------------------------------
// init: ktu[0] = colsum(K)/16384 (u0=1/16384), pads=1; zero stamps/counters.
// flags: [1]=u_sel (2=uniform u0). flags2[ii]=per-iter bad. rcnt[ii]=reducers
// done with iter ii. pst[b*16]=producer stamp (64B padded).
// ---------------------------------------------------------------------------
__launch_bounds__(128)
__global__ void k_init(const float* __restrict__ cpart, float* __restrict__ ktu0,
                       float* __restrict__ vcom, int* __restrict__ flags,
                       int* __restrict__ pst, int* __restrict__ rcnt,
                       int* __restrict__ flags2)
{
    const int j = blockIdx.x * 128 + threadIdx.x;   // 0..1023
    if (j < N_COLS) {
        float s = 0.f;
        for (int p = 0; p < 128; ++p) s += cpart[(size_t)p * N_COLS_P + j];
        ktu0[j] = s * (1.f / 16384.f);
        vcom[j] = 1.f / 1000.f;
    } else {
        ktu0[j] = 1.f;                 // pad: b=0 -> v=0 (finite)
        vcom[j] = 0.f;
    }
    for (int z = j; z < PBLK * 16; z += 1024) pst[z] = 0;
    if (j < 128) { rcnt[j] = 0; flags2[j] = 0; }
    if (j < 4)   flags[j] = (j == 1) ? 2 : 0;
}

// ---------------------------------------------------------------------------
// Persistent Sinkhorn, stamp+counter protocol, contention-hardened:
//  - producer stamps padded to 64B lines (1 writer/line);
//  - reducer wave w polls/consumes ONLY its 32 producers (overlap with skew);
//  - reducers finish with atomicAdd(rcnt[ii]) -> blocks poll ONE line,
//    one lane per block, s_sleep-paced.
// 256 blocks x 512 thr, 1 block/CU; lane owns col pairs {128q+2*lane+e};
// packed bf16 K in 64 VGPRs.
// ---------------------------------------------------------------------------
__launch_bounds__(PTHR, 2)
__global__ void k_persist(const unsigned short* __restrict__ Kb,
                          const float* __restrict__ ratios,
                          float* __restrict__ ktu,      // [2][1024]
                          float* __restrict__ utmp,     // [2][16384]
                          float* __restrict__ vcom,     // [1024]
                          float* __restrict__ partials, // [256][1024]
                          int* __restrict__ flags,
                          int* __restrict__ pst,        // [256*16] padded stamps
                          int* __restrict__ rcnt,       // [128] per-iter counter
                          int* __restrict__ flags2)     // [128] per-iter bad
{
    __shared__ float vbuf[2][N_COLS_P];
    __shared__ float wp[8][N_COLS_P];
    __shared__ float redw[8][16];
    __shared__ float rbc;
    __shared__ int ibc;
    const int t = threadIdx.x, lane = t & 63, wid = t >> 6, b = blockIdx.x;
    const int row0 = (b << 6) + (wid << 3);
    const bool isred = (b < NRED);

    // K preload: packed bf16 pairs, coalesced dword loads (plain/cached).
    unsigned kp[8][8];
#pragma unroll
    for (int r = 0; r < 8; ++r) {
        const unsigned* rp = (const unsigned*)(Kb + (size_t)(row0 + r) * N_COLS_P);
#pragma unroll
        for (int q = 0; q < 8; ++q) kp[r][q] = rp[(q << 6) + lane];
    }
    const float bj0 = (t < N_COLS) ? ratios[t] * 16384.f : 0.f;
    const float bj1 = (t + PTHR < N_COLS) ? ratios[t + PTHR] * 16384.f : 0.f;

    int usel = 2;

    for (int ii = 0; ii <= N_ITER; ++ii) {
        const int p = ii & 1;
        float kc0, kc1;

        if (ii > 0) {
            // ---- top: single-lane poll of the aggregated counter ----
            if (t == 0) {
                while (ldi_sc1(&rcnt[ii - 1]) < NRED) __builtin_amdgcn_s_sleep(1);
                ibc = ldi_sc1(&flags2[ii - 1]);
            }
            __syncthreads();
            if (ibc) break;               // bad(ii-1): revert to parity(ii-2)
            usel = (ii - 1) & 1;          // commit iter ii-1
            kc0 = ldf_sc1(&ktu[(p << 10) + t]);
            kc1 = ldf_sc1(&ktu[(p << 10) + t + PTHR]);
            if (((ii - 1) % 10) == 0) {   // convergence check of iter ii-1
                const float vo0 = vbuf[usel][t], vo1 = vbuf[usel][t + PTHR];
                const float d0 = (t < N_COLS) ? kc0 * vo0 - bj0 : 0.f;
                const float d1 = (t + PTHR < N_COLS) ? kc1 * vo1 - bj1 : 0.f;
                float e = d0 * d0 + d1 * d1;
#pragma unroll
                for (int sh = 1; sh <= 32; sh <<= 1) e += __shfl_xor(e, sh);
                if (lane == 0) redw[wid][0] = e;
                __syncthreads();
                if (t == 0) {
                    float s = 0.f;
#pragma unroll
                    for (int w = 0; w < 8; ++w) s += redw[w][0];
                    rbc = s;
                }
                __syncthreads();
                if (rbc < 1e-18f) break;  // converged at ii-1 (committed)
            }
            if (ii == N_ITER) break;      // epilogue-only pass
        } else {
            kc0 = ldf_sc1(&ktu[t]);
            kc1 = ldf_sc1(&ktu[t + PTHR]);
        }

        // ---- phase A: vnew (uniform badv check) ----
        const float v0 = bj0 / kc0;
        const float v1 = bj1 / kc1;
        const int badv = (kc0 == 0.f) | (kc1 == 0.f) | (!isfinite(v0)) | (!isfinite(v1));
        vbuf[p][t] = v0;
        vbuf[p][t + PTHR] = v1;
        if (__syncthreads_or(badv)) break;   // uniform: revert to parity(ii-1)

        float vr[16];
#pragma unroll
        for (int q = 0; q < 8; ++q) {
            const f32x2_t vv = *(const f32x2_t*)&vbuf[p][(q << 7) + (lane << 1)];
            vr[2*q] = vv[0]; vr[2*q+1] = vv[1];
        }
        float dots[8];
#pragma unroll
        for (int r = 0; r < 8; ++r) {
            float p0 = 0.f, p1 = 0.f, p2 = 0.f, p3 = 0.f;
#pragma unroll
            for (int q = 0; q < 8; ++q) {
                const unsigned u = kp[r][q];
                const float lo = __builtin_bit_cast(float, u << 16);
                const float hi = __builtin_bit_cast(float, u & 0xFFFF0000u);
                if (q & 1) { p2 = fmaf(lo, vr[2*q], p2); p3 = fmaf(hi, vr[2*q+1], p3); }
                else       { p0 = fmaf(lo, vr[2*q], p0); p1 = fmaf(hi, vr[2*q+1], p1); }
            }
            dots[r] = (p0 + p1) + (p2 + p3);
        }
#pragma unroll
        for (int s = 1; s <= 32; s <<= 1) {
#pragma unroll
            for (int r = 0; r < 8; ++r) dots[r] += __shfl_xor(dots[r], s);
        }
        float u8[8];
        int ubad = 0;
#pragma unroll
        for (int r = 0; r < 8; ++r) { u8[r] = 1.f / dots[r]; ubad |= !isfinite(u8[r]); }
        if (lane == 0) {
            float* uo = utmp + ((size_t)p << 14) + row0;
#pragma unroll
            for (int r = 0; r < 8; ++r) uo[r] = u8[r];
        }
        if (__any(ubad) && lane == 0)
            __hip_atomic_fetch_or(&flags2[ii], 1, __ATOMIC_RELAXED,
                                  __HIP_MEMORY_SCOPE_AGENT);

        float creg[16];
#pragma unroll
        for (int e = 0; e < 16; ++e) creg[e] = 0.f;
#pragma unroll
        for (int r = 0; r < 8; ++r) {
#pragma unroll
            for (int q = 0; q < 8; ++q) {
                const unsigned u = kp[r][q];
                const float lo = __builtin_bit_cast(float, u << 16);
                const float hi = __builtin_bit_cast(float, u & 0xFFFF0000u);
                creg[2*q]   = fmaf(lo, u8[r], creg[2*q]);
                creg[2*q+1] = fmaf(hi, u8[r], creg[2*q+1]);
            }
        }
#pragma unroll
        for (int q = 0; q < 8; ++q)
            *(f32x2_t*)&wp[wid][(q << 7) + (lane << 1)] = (f32x2_t){creg[2*q], creg[2*q+1]};
        __syncthreads();
        {
            const int j2 = t << 1;
            f32x2_t s2 = *(const f32x2_t*)&wp[0][j2];
#pragma unroll
            for (int w = 1; w < 8; ++w) {
                const f32x2_t x = *(const f32x2_t*)&wp[w][j2];
                s2[0] += x[0]; s2[1] += x[1];
            }
            st2_sc1(&partials[((size_t)b << 10) + j2], s2[0], s2[1]);
        }
        drain_vmem();                     // own stores (incl. flags2 or) at L3
        __syncthreads();                  // all waves drained
        if (t == 0) sti_sc1(&pst[b << 4], ii + 1);   // padded stamp, 1 line

        // ---- phase B: reducers; wave w consumes producers 32w..32w+31 ----
        if (isred) {
            {
                const int prod = (wid << 5) + (lane & 31);  // this wave's group
                const int pidx = prod << 4;
                for (;;) {
                    const int ok = (lane < 32) ? (ldi_sc1(&pst[pidx]) >= ii + 1) : 1;
                    if (__all(ok)) break;
                    __builtin_amdgcn_s_sleep(2);
                }
            }
            const int col = (b << 4) + (lane & 15);
            const int r0 = (wid << 5) + (lane >> 4);        // rows r0 + 4k
            float s = 0.f;
#pragma unroll
            for (int k = 0; k < 8; ++k)
                s += ldf_sc1(&partials[((size_t)(r0 + (k << 2)) << 10) + col]);
            s += __shfl_xor(s, 16);
            s += __shfl_xor(s, 32);
            if (lane < 16) redw[wid][lane] = s;
            __syncthreads();
            if (t < 16) {
                float s2 = 0.f;
#pragma unroll
                for (int w = 0; w < 8; ++w) s2 += redw[w][t];
                const int c = (b << 4) + t;
                stf_sc1(&ktu[(((ii + 1) & 1) << 10) + c], (c < N_COLS) ? s2 : 1.f);
            }
            drain_vmem();
            __syncthreads();
            if (t == 0)
                __hip_atomic_fetch_add(&rcnt[ii], 1, __ATOMIC_RELAXED,
                                       __HIP_MEMORY_SCOPE_AGENT);
        }
    }

    // ---- epilogue: block 0 materializes committed v and u_sel ----
    if (b == 0) {
        float vf0, vf1;
        if (usel == 2) { vf0 = 1.f / 1000.f; vf1 = 1.f / 1000.f; }
        else           { vf0 = vbuf[usel][t]; vf1 = vbuf[usel][t + PTHR]; }
        if (t < N_COLS) vcom[t] = vf0;
        if (t + PTHR < N_COLS) vcom[t + PTHR] = vf1;
        if (t == 0) flags[1] = usel;
    }
}

extern "C" void kernel_launch(void* const* d_in, const int* in_sizes, int n_in,
                              void* d_out, int out_size, void* d_ws, size_t ws_size,
                              hipStream_t stream)
{
    const float* F      = (const float*)d_in[0];
    const float* T      = (const float*)d_in[1];
    const float* ratios = (const float*)d_in[2];
    float* out = (float*)d_out;
    unsigned short* Kb = (unsigned short*)d_out;   // bf16 K, stride 1024

    float* ws        = (float*)d_ws;
    float* partials  = ws;                                   // 256*1024
    float* ktu       = partials + (size_t)PBLK * N_COLS_P;   // 2*1024
    float* utmp      = ktu + 2 * N_COLS_P;                   // 2*16384
    float* vcom      = utmp + 2 * N_ROWS;                    // 1024
    int*   flags     = (int*)(vcom + N_COLS_P);              // 4
    int*   pst       = flags + 4;                            // 256*16 padded
    int*   rcnt      = pst + PBLK * 16;                      // 128
    int*   flags2    = rcnt + 128;                           // 128
    const size_t need_bytes = ((size_t)PBLK * N_COLS_P + 2 * N_COLS_P + 2 * N_ROWS +
                               N_COLS_P) * sizeof(float) +
                              (4 + PBLK * 16 + 128 + 128) * sizeof(int);
    if (ws_size < need_bytes) return;

    k_gemm<0><<<dim3(128, 8), 256, 0, stream>>>(F, T, Kb, partials, nullptr, nullptr, flags);
    k_init<<<8, 128, 0, stream>>>(partials, ktu, vcom, flags, pst, rcnt, flags2);
    k_persist<<<PBLK, PTHR, 0, stream>>>(Kb, ratios, ktu, utmp, vcom, partials,
                                         flags, pst, rcnt, flags2);
    k_gemm<1><<<dim3(128, 8), 256, 0, stream>>>(F, T, out, nullptr, vcom, utmp, flags);
}